// Round 1
// baseline (424.752 us; speedup 1.0000x reference)
//
#include <hip/hip_runtime.h>
#include <stdint.h>

typedef __bf16 bf16;
typedef bf16 bf16x8 __attribute__((ext_vector_type(8)));
typedef bf16 bf16x4 __attribute__((ext_vector_type(4)));
typedef float f32x4 __attribute__((ext_vector_type(4)));

#define GRID_H 512
#define GRID_W 512
#define FD 64
#define HD 256

// ---- ws layout (bytes) ----
#define WS_W1F 0          // 32768  : 32 blocks of 1KB, block id = kt*16+mt (kt<2)
#define WS_W2F 32768      // 131072 : 128 blocks, block id = kt*16+mt (kt<8)
#define WS_W3P 163840     // 4096   : 256 x float4 (w3 row padded)

// ---- LDS layout (bytes) ----
#define LDS_FEATS 0       // 8192  : featsT B-frags, block (ptile*2+kt)
#define LDS_H1    8192    // 32768 : h1T  B-frags, block (ptile*8+kt)
#define LDS_WST   40960   // 32768 : weight staging (W1 whole / W2 2x16KB halves)
#define LDS_SIZE  73728

__device__ __forceinline__ f32x4 mfma16(bf16x8 a, bf16x8 b, f32x4 c) {
  return __builtin_amdgcn_mfma_f32_16x16x32_bf16(a, b, c, 0, 0, 0);
}

// Convert weights to bf16 fragment-linear layout.
// Fragment convention (assumed consistently for A and B operands):
//   position (lane, j) <-> k = 32*kt + 8*(lane>>4) + j ; m/n = 16*mt + (lane&15)
__global__ __launch_bounds__(256) void nf_prep(
    const float* __restrict__ W1, const float* __restrict__ W2,
    const float* __restrict__ W3,
    bf16* __restrict__ w1f, bf16* __restrict__ w2f, float4* __restrict__ w3p)
{
  int t = blockIdx.x * 256 + threadIdx.x;
  if (t < 16384) {                       // W1^T frags: A[m=out][k=in] = W1[k][m]
    int e = t, blk = e >> 9, el = e & 511;
    int lane = el >> 3, j = el & 7;
    int kt = blk >> 4, mt = blk & 15;
    int k = kt * 32 + (lane >> 4) * 8 + j;   // in-ch < 64
    int m = mt * 16 + (lane & 15);           // out-ch < 256
    w1f[e] = (bf16)W1[k * HD + m];
  } else if (t < 16384 + 65536) {        // W2^T frags
    int e = t - 16384, blk = e >> 9, el = e & 511;
    int lane = el >> 3, j = el & 7;
    int kt = blk >> 4, mt = blk & 15;
    int k = kt * 32 + (lane >> 4) * 8 + j;   // in-ch < 256
    int m = mt * 16 + (lane & 15);           // out-ch < 256
    w2f[e] = (bf16)W2[k * HD + m];
  } else if (t < 16384 + 65536 + 256) {  // W3 rows padded to float4
    int c = t - 16384 - 65536;
    w3p[c] = make_float4(W3[c * 3 + 0], W3[c * 3 + 1], W3[c * 3 + 2], 0.f);
  }
}

// Fused: bilinear sample -> L1 -> L2 -> L3.  64 points/block, 256 threads (4 waves).
// Transposed GEMM form: A = W^T (m = channels), B = activations^T (n = points).
__global__ __launch_bounds__(256) void nf_fused(
    const float* __restrict__ coords, const float* __restrict__ grid,
    const float* __restrict__ b1, const float* __restrict__ b2,
    const float* __restrict__ b3,
    const bf16* __restrict__ w1f, const bf16* __restrict__ w2f,
    const float4* __restrict__ w3p, float* __restrict__ out)
{
  __shared__ __align__(16) unsigned char lds[LDS_SIZE];
  const int tid = threadIdx.x;
  const int w = tid >> 6;        // wave id = point-tile
  const int l = tid & 63;
  const int g = l >> 4;          // lane group
  const int r15 = l & 15;

  // ---------- phase 0a: stage all W1 frags (32KB flat copy) ----------
  {
    const uint4* src = (const uint4*)w1f;
    uint4* dst = (uint4*)(lds + LDS_WST);
#pragma unroll
    for (int i = 0; i < 8; ++i) dst[i * 256 + tid] = src[i * 256 + tid];
  }

  // ---------- phase 0b: bilinear sample -> featsT B-frags ----------
  {
    int p_local = tid >> 2;          // 0..63
    int cg = tid & 3;                // channel group of 16
    int pIdx = blockIdx.x * 64 + p_local;
    float cx = coords[2 * pIdx + 0];
    float cy = coords[2 * pIdx + 1];
    float px = (cx * 0.5f + 0.5f) * (float)(GRID_W - 1);
    float py = (cy * 0.5f + 0.5f) * (float)(GRID_H - 1);
    float fx = fminf(fmaxf(floorf(px), 0.f), (float)(GRID_W - 2));
    float fy = fminf(fmaxf(floorf(py), 0.f), (float)(GRID_H - 2));
    int x0 = (int)fx, y0 = (int)fy;
    float tx = px - fx, ty = py - fy;
    float w00 = (1.f - tx) * (1.f - ty);
    float w01 = tx * (1.f - ty);
    float w10 = (1.f - tx) * ty;
    float w11 = tx * ty;

    const float4* g00 = (const float4*)grid + (y0 * GRID_W + x0) * (FD / 4) + cg * 4;
    const float4* g01 = g00 + (FD / 4);
    const float4* g10 = g00 + GRID_W * (FD / 4);
    const float4* g11 = g10 + (FD / 4);

    bf16x8 lo, hi;
#pragma unroll
    for (int q = 0; q < 4; ++q) {
      float4 a = g00[q], b = g01[q], c = g10[q], d = g11[q];
      float f0 = a.x * w00 + b.x * w01 + c.x * w10 + d.x * w11;
      float f1 = a.y * w00 + b.y * w01 + c.y * w10 + d.y * w11;
      float f2 = a.z * w00 + b.z * w01 + c.z * w10 + d.z * w11;
      float f3 = a.w * w00 + b.w * w01 + c.w * w10 + d.w * w11;
      if (q < 2) {
        lo[q * 4 + 0] = (bf16)f0; lo[q * 4 + 1] = (bf16)f1;
        lo[q * 4 + 2] = (bf16)f2; lo[q * 4 + 3] = (bf16)f3;
      } else {
        hi[(q - 2) * 4 + 0] = (bf16)f0; hi[(q - 2) * 4 + 1] = (bf16)f1;
        hi[(q - 2) * 4 + 2] = (bf16)f2; hi[(q - 2) * 4 + 3] = (bf16)f3;
      }
    }
    // frag byte addr for (ch = cg*16 + c, point p_local):
    // block = (p>>4)*2 + (ch>>5); lane' = ((ch>>3)&3)*16 + (p&15); byte = blk*1024 + lane'*16 + (ch&7)*2
    int byte0 = LDS_FEATS + ((p_local >> 4) * 2 + (cg >> 1)) * 1024 +
                ((((2 * cg) & 3) * 16) + (p_local & 15)) * 16;
    *(bf16x8*)(lds + byte0) = lo;
    *(bf16x8*)(lds + byte0 + 256) = hi;
  }

  __syncthreads();

  // ---------- layer 1: h1^T = relu(W1^T @ feats^T + b1) ----------
  f32x4 acc1[16];
#pragma unroll
  for (int mt = 0; mt < 16; ++mt) acc1[mt] = (f32x4){0.f, 0.f, 0.f, 0.f};

#pragma unroll
  for (int kt = 0; kt < 2; ++kt) {
    bf16x8 bfr = *(const bf16x8*)(lds + LDS_FEATS + (w * 2 + kt) * 1024 + l * 16);
    const unsigned char* abase = lds + LDS_WST + kt * 16384 + l * 16;
#pragma unroll
    for (int mt = 0; mt < 16; ++mt) {
      bf16x8 af = *(const bf16x8*)(abase + mt * 1024);
      acc1[mt] = mfma16(af, bfr, acc1[mt]);
    }
  }

  // epilogue: relu(acc1 + b1) -> bf16 -> h1T B-frags in LDS
  // lane holds D rows (ch = mt*16 + 4g + r), col (point = w*16 + r15)
#pragma unroll
  for (int mt = 0; mt < 16; ++mt) {
    float4 b1v = *(const float4*)(b1 + mt * 16 + 4 * g);
    bf16x4 hv;
    hv[0] = (bf16)fmaxf(acc1[mt][0] + b1v.x, 0.f);
    hv[1] = (bf16)fmaxf(acc1[mt][1] + b1v.y, 0.f);
    hv[2] = (bf16)fmaxf(acc1[mt][2] + b1v.z, 0.f);
    hv[3] = (bf16)fmaxf(acc1[mt][3] + b1v.w, 0.f);
    // ch_base = mt*16 + 4g ; kt2 = mt>>1 ; c3 = (2mt + (g>>1))&3 ; j0 = 4*(g&1)
    int byteoff = LDS_H1 + (w * 8 + (mt >> 1)) * 1024 +
                  ((((2 * mt + (g >> 1)) & 3) * 16) + r15) * 16 + (g & 1) * 8;
    *(bf16x4*)(lds + byteoff) = hv;
  }

  __syncthreads();   // W1 reads done, h1 written -> WST reusable

  // ---------- layer 2: h2^T = relu(W2^T @ h1^T + b2), W2 staged in 16KB k-chunks ----------
  {
    const uint4* src = (const uint4*)w2f;   // chunk kt = bytes [kt*16384, +16384)
    uint4* dst = (uint4*)(lds + LDS_WST);
#pragma unroll
    for (int i = 0; i < 4; ++i) dst[i * 256 + tid] = src[i * 256 + tid];
  }
  __syncthreads();

  f32x4 acc2[16];
#pragma unroll
  for (int mt = 0; mt < 16; ++mt) acc2[mt] = (f32x4){0.f, 0.f, 0.f, 0.f};

  for (int kt = 0; kt < 8; ++kt) {
    uint4 pre0, pre1, pre2, pre3;
    if (kt < 7) {   // prefetch next chunk into regs (hide behind MFMA)
      const uint4* src = (const uint4*)((const unsigned char*)w2f + (kt + 1) * 16384);
      pre0 = src[0 * 256 + tid];
      pre1 = src[1 * 256 + tid];
      pre2 = src[2 * 256 + tid];
      pre3 = src[3 * 256 + tid];
    }
    bf16x8 bfr = *(const bf16x8*)(lds + LDS_H1 + (w * 8 + kt) * 1024 + l * 16);
    const unsigned char* abase = lds + LDS_WST + (kt & 1) * 16384 + l * 16;
#pragma unroll
    for (int mt = 0; mt < 16; ++mt) {
      bf16x8 af = *(const bf16x8*)(abase + mt * 1024);
      acc2[mt] = mfma16(af, bfr, acc2[mt]);
    }
    if (kt < 7) {
      uint4* dst = (uint4*)(lds + LDS_WST + ((kt + 1) & 1) * 16384);
      dst[0 * 256 + tid] = pre0;
      dst[1 * 256 + tid] = pre1;
      dst[2 * 256 + tid] = pre2;
      dst[3 * 256 + tid] = pre3;
    }
    __syncthreads();
  }

  // ---------- layer 3 (fp32, in registers): out = relu(h2) @ W3 + b3 ----------
  float o0 = 0.f, o1 = 0.f, o2 = 0.f;
#pragma unroll
  for (int mt = 0; mt < 16; ++mt) {
    float4 b2v = *(const float4*)(b2 + mt * 16 + 4 * g);
    float4 w3a = w3p[mt * 16 + 4 * g + 0];
    float4 w3b = w3p[mt * 16 + 4 * g + 1];
    float4 w3c = w3p[mt * 16 + 4 * g + 2];
    float4 w3d = w3p[mt * 16 + 4 * g + 3];
    float h0 = fmaxf(acc2[mt][0] + b2v.x, 0.f);
    float h1v = fmaxf(acc2[mt][1] + b2v.y, 0.f);
    float h2v = fmaxf(acc2[mt][2] + b2v.z, 0.f);
    float h3 = fmaxf(acc2[mt][3] + b2v.w, 0.f);
    o0 += h0 * w3a.x + h1v * w3b.x + h2v * w3c.x + h3 * w3d.x;
    o1 += h0 * w3a.y + h1v * w3b.y + h2v * w3c.y + h3 * w3d.y;
    o2 += h0 * w3a.z + h1v * w3b.z + h2v * w3c.z + h3 * w3d.z;
  }
  // reduce over the 4 lane-groups holding the same point (lanes l, l^16, l^32, l^48)
  o0 += __shfl_xor(o0, 16); o0 += __shfl_xor(o0, 32);
  o1 += __shfl_xor(o1, 16); o1 += __shfl_xor(o1, 32);
  o2 += __shfl_xor(o2, 16); o2 += __shfl_xor(o2, 32);

  if (g == 0) {
    int p = blockIdx.x * 64 + w * 16 + r15;
    float* op = out + p * 3;
    op[0] = o0 + b3[0];
    op[1] = o1 + b3[1];
    op[2] = o2 + b3[2];
  }
}

extern "C" void kernel_launch(void* const* d_in, const int* in_sizes, int n_in,
                              void* d_out, int out_size, void* d_ws, size_t ws_size,
                              hipStream_t stream) {
  const float* coords = (const float*)d_in[0];
  const float* grid_p = (const float*)d_in[1];
  const float* W1 = (const float*)d_in[2];
  const float* b1 = (const float*)d_in[3];
  const float* W2 = (const float*)d_in[4];
  const float* b2 = (const float*)d_in[5];
  const float* W3 = (const float*)d_in[6];
  const float* b3 = (const float*)d_in[7];
  float* out = (float*)d_out;

  bf16* w1f = (bf16*)((unsigned char*)d_ws + WS_W1F);
  bf16* w2f = (bf16*)((unsigned char*)d_ws + WS_W2F);
  float4* w3p = (float4*)((unsigned char*)d_ws + WS_W3P);

  int N = in_sizes[0] / 2;          // coords is (N,2)
  int nBlocks = N / 64;             // N = 1<<20 divides evenly

  nf_prep<<<321, 256, 0, stream>>>(W1, W2, W3, w1f, w2f, w3p);
  nf_fused<<<nBlocks, 256, 0, stream>>>(coords, grid_p, b1, b2, b3,
                                        w1f, w2f, w3p, out);
}